// Round 6
// baseline (306.913 us; speedup 1.0000x reference)
//
#include <hip/hip_runtime.h>
#include <hip/hip_bf16.h>
#include <math.h>

// Problem constants
#define TT   4096     // T
#define BB   16       // B
#define NTOK 65536    // B*T
#define CIN  512      // IN_FEATS
#define EF   256      // EMBED_FEATS
#define NE   1024     // NUM_EMBED

typedef __attribute__((ext_vector_type(8))) short bf16x8;
typedef __attribute__((ext_vector_type(4))) float f32x4;

static __device__ __forceinline__ unsigned short f2bf(float f) {
  unsigned int u = __float_as_uint(f);
  u += 0x7fffu + ((u >> 16) & 1u);          // RNE
  return (unsigned short)(u >> 16);
}

// async global->LDS, 16B per lane; LDS dest is wave-uniform base + lane*16
#define GLL(gsrc, ldst) \
  __builtin_amdgcn_global_load_lds((const __attribute__((address_space(1))) void*)(gsrc), \
                                   (__attribute__((address_space(3))) void*)(ldst), 16, 0, 0)

// ---------------------------------------------------------------------------
// K0: convert proj_w -> bf16; embed -> bf16*(-2); e_norm[k] = ||embed_k||^2
// ---------------------------------------------------------------------------
__global__ __launch_bounds__(256) void k_prep(const float* __restrict__ Wf,
                                              const float* __restrict__ Ef,
                                              unsigned short* __restrict__ Wbf,
                                              unsigned short* __restrict__ Ebf,
                                              float* __restrict__ e_norm) {
  int bid = blockIdx.x;
  if (bid < 512) {                      // W: 256*512 = 131072 elems
    int i = bid * 256 + threadIdx.x;
    Wbf[i] = f2bf(Wf[i]);
  } else if (bid < 1536) {              // E scaled by -2 (exact): 262144 elems
    int i = (bid - 512) * 256 + threadIdx.x;
    Ebf[i] = f2bf(-2.0f * Ef[i]);
  } else {                              // e_norm: 256 blocks * 4 codes (1 wave/code)
    int w = threadIdx.x >> 6, l = threadIdx.x & 63;
    int k = (bid - 1536) * 4 + w;
    const float4 v4 = ((const float4*)(Ef + (size_t)k * EF))[l];
    float s = v4.x * v4.x + v4.y * v4.y + v4.z * v4.z + v4.w * v4.w;
    for (int off = 32; off; off >>= 1) s += __shfl_down(s, off);
    if (l == 0) e_norm[k] = s;
  }
}

// ---------------------------------------------------------------------------
// K1: projection GEMM. 64 tokens / 256 threads / block, 1024 blocks.
// LDS 40 KB (as 8K + bs 32K; xs 32K aliased) -> 4 blocks/CU, 16 waves/CU.
// (256,2) -> 128 VGPR (measured R2: uses 108, no spills).
// phase1: A (in^T) transposed+converted in regs -> swizzled LDS; W via GLL.
// phase2: x+bias -> xsq, bf16 -> swizzled xs -> vectorized 16B stores to x_bf
//         (PLAIN row layout [tok][256] so k_dist can load A-frags directly).
// ---------------------------------------------------------------------------
__global__ __launch_bounds__(256, 2) void k_gemm1(const float* __restrict__ in,
                                                  const unsigned short* __restrict__ Wbf,
                                                  const float* __restrict__ bias,
                                                  unsigned short* __restrict__ x_bf,
                                                  float* __restrict__ sse) {
  __shared__ unsigned short lds[20480];   // 40 KB
  unsigned short* as_ = lds;              // A [64 t][64 c]    8 KB
  unsigned short* bs  = lds + 4096;       // W [256 e][64 c]  32 KB
  unsigned short* xs  = lds;              // x [64 t][256 e]  32 KB (aliased)

  int tid = threadIdx.x;
  int w = tid >> 6, l = tid & 63;
  int l15 = l & 15, quad = l >> 4;
  int tok0 = blockIdx.x * 64;
  const float* src = in + (size_t)(tok0 >> 12) * CIN * TT + (tok0 & 4095);

  f32x4 acc[4][4];
#pragma unroll
  for (int a = 0; a < 4; ++a)
#pragma unroll
    for (int b = 0; b < 4; ++b) acc[a][b] = (f32x4){0.f, 0.f, 0.f, 0.f};

  float v[16];
  {
    const float* s0 = src + (size_t)(w * 16) * TT + l;
#pragma unroll
    for (int i = 0; i < 16; ++i) v[i] = s0[(size_t)i * TT];
  }
  for (int ks = 0; ks < 8; ++ks) {
    int k0 = ks * 64;
    // W stage: 2048 16B chunks via GLL (8 per thread)
#pragma unroll
    for (int i = 0; i < 8; ++i) {
      int g = i * 256 + tid;
      int row = g >> 3, pc = g & 7, lc = pc ^ (row & 7);
      GLL(Wbf + (size_t)row * CIN + k0 + lc * 8, bs + g * 8);
    }
    // A: convert, swizzled b128 LDS writes (row = t = l)
#pragma unroll
    for (int cc = 0; cc < 2; ++cc) {
      alignas(16) unsigned short tmp[8];
#pragma unroll
      for (int j = 0; j < 8; ++j) tmp[j] = f2bf(v[cc * 8 + j]);
      int c8 = w * 2 + cc;
      int pc = c8 ^ (l & 7);
      *(bf16x8*)(as_ + l * 64 + pc * 8) = *(const bf16x8*)tmp;
    }
    __syncthreads();
    if (ks < 7) {       // prefetch next A in flight across MFMA window
      const float* s0 = src + (size_t)(k0 + 64 + w * 16) * TT + l;
#pragma unroll
      for (int i = 0; i < 16; ++i) v[i] = s0[(size_t)i * TT];
    }
#pragma unroll
    for (int kstep = 0; kstep < 2; ++kstep) {
      int ck = kstep * 4 + quad;
      bf16x8 af[4], bfr[4];
#pragma unroll
      for (int msub = 0; msub < 4; ++msub) {
        int row = msub * 16 + l15;
        int pa = ck ^ (row & 7);
        af[msub] = *(const bf16x8*)(as_ + row * 64 + pa * 8);
      }
#pragma unroll
      for (int nsub = 0; nsub < 4; ++nsub) {
        int row = w * 64 + nsub * 16 + l15;
        int pb = ck ^ (row & 7);
        bfr[nsub] = *(const bf16x8*)(bs + row * 64 + pb * 8);
      }
#pragma unroll
      for (int msub = 0; msub < 4; ++msub)
#pragma unroll
        for (int nsub = 0; nsub < 4; ++nsub)
          acc[msub][nsub] = __builtin_amdgcn_mfma_f32_16x16x32_bf16(af[msub], bfr[nsub],
                                                                    acc[msub][nsub], 0, 0, 0);
    }
    __syncthreads();
  }

  // phase 2: bias, xsq, bf16 -> xs (swizzled), then vector stores to x_bf
  float xsq = 0.f;
#pragma unroll
  for (int nsub = 0; nsub < 4; ++nsub) {
    int e = w * 64 + nsub * 16 + l15;
    float bv = bias[e];
    int cx = e >> 3;
#pragma unroll
    for (int msub = 0; msub < 4; ++msub)
#pragma unroll
      for (int reg = 0; reg < 4; ++reg) {
        int m = msub * 16 + quad * 4 + reg;
        float x = acc[msub][nsub][reg] + bv;
        xsq += x * x;
        int pcx = cx ^ (m & 31);
        xs[m * 256 + pcx * 8 + (e & 7)] = f2bf(x);
      }
  }
  __syncthreads();
#pragma unroll
  for (int i = 0; i < 8; ++i) {         // 2048 chunks: read swizzled, store plain
    int g = i * 256 + tid;
    int m = g >> 5, c = g & 31;
    int pcx = c ^ (m & 31);
    bf16x8 val = *(const bf16x8*)(xs + m * 256 + pcx * 8);
    *(bf16x8*)(x_bf + (size_t)(tok0 + m) * EF + c * 8) = val;
  }
  // xsq reduce -> one atomic
  __shared__ float xred[4];
  for (int off = 32; off; off >>= 1) xsq += __shfl_down(xsq, off);
  if (l == 0) xred[w] = xsq;
  __syncthreads();
  if (tid == 0) atomicAdd(sse, xred[0] + xred[1] + xred[2] + xred[3]);
}

// ---------------------------------------------------------------------------
// K2: distances + argmin + fused gather/write. 128 tok / 256 thr / block,
// 512 blocks (exactly 2/CU resident, 64 KB LDS).
// A-frags af[2][8] loaded DIRECTLY from global x_bf (16B chunks = MFMA A
// layout) -- no A LDS, no A barrier. All 64 KB LDS = double-buffered embed
// stream: 16 chunks x 64 codes, one barrier/chunk, 64 MFMA/wave between.
// Wave w owns tokens [tok0+32w, +32): argmin is wave-local (all codes seen).
// Epilogue: bi -> LDS, hist/sse atomics, then z_q gather + transposed write
// (4 passes of 64 e through a 128x65 f32 LDS buffer, reusing es space).
// (256,1): ample VGPR (af 64 + dacc 32 + best 16), LDS caps blocks anyway.
// ---------------------------------------------------------------------------
__global__ __launch_bounds__(256, 1) void k_dist(const unsigned short* __restrict__ x_bf,
                                                 const unsigned short* __restrict__ Ebf,
                                                 const float* __restrict__ e_norm,
                                                 const float* __restrict__ embed,
                                                 float* __restrict__ out,
                                                 unsigned int* __restrict__ hist,
                                                 float* __restrict__ sse) {
  __shared__ unsigned short lds[32768];   // 64 KB: es dbuf 2x32KB; later zq
  float* zq    = (float*)lds;             // [128][65] = 33.3 KB
  int* idxs    = (int*)(lds + 30720);     // 128 ints @ byte 61440
  float* svred = (float*)(lds + 31488);   // 4 floats @ byte 62976

  int tid = threadIdx.x;
  int w = tid >> 6, l = tid & 63;
  int l15 = l & 15, quad = l >> 4;
  int tok0 = blockIdx.x * 128;

  // A-fragments straight from global (x_bf row-major): 16 loads, in flight
  bf16x8 af[2][8];
#pragma unroll
  for (int msub = 0; msub < 2; ++msub)
#pragma unroll
    for (int kst = 0; kst < 8; ++kst) {
      int row = tok0 + w * 32 + msub * 16 + l15;
      af[msub][kst] = *(const bf16x8*)(x_bf + (size_t)row * EF + (kst * 4 + quad) * 8);
    }

  // stage chunk 0 (64 codes x 256 k = 32 KB) into buf 0
#pragma unroll
  for (int i = 0; i < 8; ++i) {
    int g = i * 256 + tid;
    int row = g >> 5, pcc = g & 31, lc = pcc ^ (row & 31);
    GLL(Ebf + (size_t)row * EF + lc * 8, lds + g * 8);
  }
  float enn[4];
#pragma unroll
  for (int nsub = 0; nsub < 4; ++nsub) enn[nsub] = e_norm[nsub * 16 + l15];
  __syncthreads();

  float best_v[2][4];
  int best_i[2][4];
#pragma unroll
  for (int a = 0; a < 2; ++a)
#pragma unroll
    for (int b = 0; b < 4; ++b) { best_v[a][b] = 3.0e38f; best_i[a][b] = 0; }

  for (int chunk = 0; chunk < 16; ++chunk) {
    int c0 = chunk * 64;
    unsigned short* eb = lds + (chunk & 1) * 16384;
    if (chunk < 15) {                     // prefetch chunk+1 into other buf
      unsigned short* ebn = lds + ((chunk & 1) ^ 1) * 16384;
#pragma unroll
      for (int i = 0; i < 8; ++i) {
        int g = i * 256 + tid;
        int row = g >> 5, pcc = g & 31, lc = pcc ^ (row & 31);
        GLL(Ebf + (size_t)(c0 + 64 + row) * EF + lc * 8, ebn + g * 8);
      }
    }
    f32x4 dacc[2][4];
#pragma unroll
    for (int nsub = 0; nsub < 4; ++nsub) {
      float en = enn[nsub];
      dacc[0][nsub] = (f32x4){en, en, en, en};
      dacc[1][nsub] = (f32x4){en, en, en, en};
    }
    if (chunk < 15) {                     // prefetch next e_norm
#pragma unroll
      for (int nsub = 0; nsub < 4; ++nsub) enn[nsub] = e_norm[c0 + 64 + nsub * 16 + l15];
    }
#pragma unroll
    for (int nsub = 0; nsub < 4; ++nsub) {
      int n = nsub * 16 + l15;
#pragma unroll
      for (int kst = 0; kst < 8; ++kst) {
        int pc = (kst * 4 + quad) ^ (n & 31);
        bf16x8 bfr = *(const bf16x8*)(eb + n * 256 + pc * 8);
        dacc[0][nsub] = __builtin_amdgcn_mfma_f32_16x16x32_bf16(af[0][kst], bfr,
                                                                dacc[0][nsub], 0, 0, 0);
        dacc[1][nsub] = __builtin_amdgcn_mfma_f32_16x16x32_bf16(af[1][kst], bfr,
                                                                dacc[1][nsub], 0, 0, 0);
      }
    }
#pragma unroll
    for (int msub = 0; msub < 2; ++msub)
#pragma unroll
      for (int nsub = 0; nsub < 4; ++nsub) {
        int code = c0 + nsub * 16 + l15;
#pragma unroll
        for (int reg = 0; reg < 4; ++reg) {
          float vv = dacc[msub][nsub][reg];
          if (vv < best_v[msub][reg]) { best_v[msub][reg] = vv; best_i[msub][reg] = code; }
        }
      }
    __syncthreads();
  }

  // wave-local argmin across the 16 l15 lanes
  float sv = 0.f;
#pragma unroll
  for (int msub = 0; msub < 2; ++msub)
#pragma unroll
    for (int reg = 0; reg < 4; ++reg) {
      float vv = best_v[msub][reg];
      int idx = best_i[msub][reg];
#pragma unroll
      for (int off = 8; off; off >>= 1) {
        float ov = __shfl_xor(vv, off, 16);
        int oi = __shfl_xor(idx, off, 16);
        if (ov < vv || (ov == vv && oi < idx)) { vv = ov; idx = oi; }
      }
      if (l15 == 0) {
        int m = w * 32 + msub * 16 + quad * 4 + reg;
        idxs[m] = idx;
        atomicAdd(&hist[idx], 1u);
        sv += vv;
      }
    }
  for (int off = 32; off; off >>= 1) sv += __shfl_down(sv, off);
  if (l == 0) svred[w] = sv;
  __syncthreads();
  if (tid == 0) atomicAdd(sse, svred[0] + svred[1] + svred[2] + svred[3]);

  // fused gather + transposed z_q write: 4 passes of 64 e
  int b = tok0 >> 12, t0 = tok0 & 4095;
  int tg = tid >> 4;
  for (int pass = 0; pass < 4; ++pass) {
    int e0 = pass * 64;
    __syncthreads();                      // zq region free (prev pass / idxs ready)
    for (int r = 0; r < 8; ++r) {
      int tl = r * 16 + tg;
      const float4 vv = *(const float4*)(embed + (size_t)idxs[tl] * EF + e0 + l15 * 4);
      float* zr = zq + tl * 65 + l15 * 4;
      zr[0] = vv.x; zr[1] = vv.y; zr[2] = vv.z; zr[3] = vv.w;
    }
    __syncthreads();
    int tl4 = (tid & 31) * 4;
    for (int r = 0; r < 8; ++r) {
      int e = r * 8 + (tid >> 5);
      float4 vv;
      vv.x = zq[(tl4 + 0) * 65 + e];
      vv.y = zq[(tl4 + 1) * 65 + e];
      vv.z = zq[(tl4 + 2) * 65 + e];
      vv.w = zq[(tl4 + 3) * 65 + e];
      *(float4*)(out + ((size_t)(b * EF + e0 + e) << 12) + t0 + tl4) = vv;
    }
  }
}

// ---------------------------------------------------------------------------
// K3: finalize scalars
// ---------------------------------------------------------------------------
__global__ __launch_bounds__(256) void k_final(const unsigned int* __restrict__ hist,
                                               const float* __restrict__ sse,
                                               float* __restrict__ out) {
  __shared__ float red[4];
  int tid = threadIdx.x;
  float local = 0.f;
  for (int i = tid; i < NE; i += 256) {
    float p = (float)hist[i] * (1.0f / 65536.0f);
    local -= p * logf(p + 1e-10f);
  }
  for (int off = 32; off; off >>= 1) local += __shfl_down(local, off);
  if ((tid & 63) == 0) red[tid >> 6] = local;
  __syncthreads();
  if (tid == 0) {
    float lp = red[0] + red[1] + red[2] + red[3];
    out[16777216] = 1.25f * sse[0] / 16777216.0f;  // vq + 0.25*commitment
    out[16777233] = lp;
  }
  if (tid < 16) out[16777217 + tid] = 6.93147180559945f * 4096.0f;  // log(1024)*4096
}

// ---------------------------------------------------------------------------
extern "C" void kernel_launch(void* const* d_in, const int* in_sizes, int n_in,
                              void* d_out, int out_size, void* d_ws, size_t ws_size,
                              hipStream_t stream) {
  const float* inputs = (const float*)d_in[0];
  const float* proj_w = (const float*)d_in[1];
  const float* proj_b = (const float*)d_in[2];
  const float* embed = (const float*)d_in[3];
  float* out = (float*)d_out;
  char* ws = (char*)d_ws;

  // workspace layout
  unsigned short* x_bf = (unsigned short*)(ws);             // 33,554,432 B
  unsigned short* Wbf  = (unsigned short*)(ws + 33554432);  //    262,144 B
  unsigned short* Ebf  = (unsigned short*)(ws + 33816576);  //    524,288 B
  float* e_norm        = (float*)(ws + 34340864);           //      4,096 B
  unsigned int* hist   = (unsigned int*)(ws + 34344960);    //      4,096 B
  float* sse           = (float*)(ws + 34349056);           //          4 B
  if (ws_size < 34349060) return;

  hipMemsetAsync(ws + 34344960, 0, 4100, stream);  // hist + sse

  k_prep<<<1792, 256, 0, stream>>>(proj_w, embed, Wbf, Ebf, e_norm);
  k_gemm1<<<1024, 256, 0, stream>>>(inputs, Wbf, proj_b, x_bf, sse);
  k_dist<<<512, 256, 0, stream>>>(x_bf, Ebf, e_norm, embed, out, hist, sse);
  k_final<<<1, 256, 0, stream>>>(hist, sse, out);
}